// Round 4
// baseline (316.423 us; speedup 1.0000x reference)
//
#include <hip/hip_runtime.h>
#include <math.h>

#define NEG_CONST (-9000000000000000.0f)
#define SCARE 11.313708498984761f  // sqrt(128)

#define DPP_XOR1  0xB1   // quad_perm [1,0,3,2]
#define DPP_XOR2  0x4E   // quad_perm [2,3,0,1]
#define DPP_XOR7  0x141  // row_half_mirror
#define DPP_XOR15 0x140  // row_mirror

template<int CTRL>
__device__ __forceinline__ float dpp_add(float x) {
    int yi = __builtin_amdgcn_update_dpp(0, __float_as_int(x), CTRL, 0xF, 0xF, true);
    return x + __int_as_float(yi);
}
template<int CTRL>
__device__ __forceinline__ float dpp_max(float x) {
    int yi = __builtin_amdgcn_update_dpp(0, __float_as_int(x), CTRL, 0xF, 0xF, true);
    return fmaxf(x, __int_as_float(yi));
}

__device__ __forceinline__ void wave_lds_fence() {
    __builtin_amdgcn_wave_barrier();
    asm volatile("s_waitcnt lgkmcnt(0)" ::: "memory");
    __builtin_amdgcn_wave_barrier();
}

// ---- kernel 1: y=0: QKt = Q @ K^T ; y=1: VV = V @ V  (grid (16,2)) ----
__global__ __launch_bounds__(256) void small_mm_a(const float* __restrict__ Q,
                                                  const float* __restrict__ K,
                                                  const float* __restrict__ V,
                                                  float* __restrict__ QKt,
                                                  float* __restrict__ VV) {
    int r  = blockIdx.x * 8 + (threadIdx.x >> 5);
    int c0 = (threadIdx.x & 31) * 4;
    float a0 = 0.f, a1 = 0.f, a2 = 0.f, a3 = 0.f;
    if (blockIdx.y == 0) {
        for (int k = 0; k < 128; k += 4) {
            float4 q  = *reinterpret_cast<const float4*>(&Q[r * 128 + k]);
            float4 k0 = *reinterpret_cast<const float4*>(&K[(c0 + 0) * 128 + k]);
            float4 k1 = *reinterpret_cast<const float4*>(&K[(c0 + 1) * 128 + k]);
            float4 k2 = *reinterpret_cast<const float4*>(&K[(c0 + 2) * 128 + k]);
            float4 k3 = *reinterpret_cast<const float4*>(&K[(c0 + 3) * 128 + k]);
            a0 += q.x*k0.x + q.y*k0.y + q.z*k0.z + q.w*k0.w;
            a1 += q.x*k1.x + q.y*k1.y + q.z*k1.z + q.w*k1.w;
            a2 += q.x*k2.x + q.y*k2.y + q.z*k2.z + q.w*k2.w;
            a3 += q.x*k3.x + q.y*k3.y + q.z*k3.z + q.w*k3.w;
        }
        float4 o = {a0, a1, a2, a3};
        *reinterpret_cast<float4*>(&QKt[r * 128 + c0]) = o;
    } else {
        for (int k = 0; k < 128; ++k) {
            float a = V[r * 128 + k];
            float4 b = *reinterpret_cast<const float4*>(&V[k * 128 + c0]);
            a0 += a * b.x; a1 += a * b.y; a2 += a * b.z; a3 += a * b.w;
        }
        float4 o = {a0, a1, a2, a3};
        *reinterpret_cast<float4*>(&VV[r * 128 + c0]) = o;
    }
}

// ---- kernel 2: MT = QKt @ V^T  (grid 16) ----
__global__ __launch_bounds__(256) void small_mm_b(const float* __restrict__ QKt,
                                                  const float* __restrict__ V,
                                                  float* __restrict__ MT) {
    int r  = blockIdx.x * 8 + (threadIdx.x >> 5);
    int c0 = (threadIdx.x & 31) * 4;
    float a0 = 0.f, a1 = 0.f, a2 = 0.f, a3 = 0.f;
    for (int k = 0; k < 128; k += 4) {
        float4 q  = *reinterpret_cast<const float4*>(&QKt[r * 128 + k]);
        float4 k0 = *reinterpret_cast<const float4*>(&V[(c0 + 0) * 128 + k]);
        float4 k1 = *reinterpret_cast<const float4*>(&V[(c0 + 1) * 128 + k]);
        float4 k2 = *reinterpret_cast<const float4*>(&V[(c0 + 2) * 128 + k]);
        float4 k3 = *reinterpret_cast<const float4*>(&V[(c0 + 3) * 128 + k]);
        a0 += q.x*k0.x + q.y*k0.y + q.z*k0.z + q.w*k0.w;
        a1 += q.x*k1.x + q.y*k1.y + q.z*k1.z + q.w*k1.w;
        a2 += q.x*k2.x + q.y*k2.y + q.z*k2.z + q.w*k2.w;
        a3 += q.x*k3.x + q.y*k3.y + q.z*k3.z + q.w*k3.w;
    }
    float4 o = {a0, a1, a2, a3};
    *reinterpret_cast<float4*>(&MT[r * 128 + c0]) = o;
}

// ---- kernel 3: P = x @ W for 4 weights; 128x128 tile, 8x8 per thread ----
__global__ __launch_bounds__(256) void proj_gemm(
    const float* __restrict__ x,
    const float* __restrict__ W0, const float* __restrict__ W1,
    const float* __restrict__ W2, const float* __restrict__ W3,
    float* __restrict__ O0, float* __restrict__ O1,
    float* __restrict__ O2, float* __restrict__ O3, int n)
{
    __shared__ __align__(16) float xs[32][132];  // [k][row] (transposed)
    __shared__ __align__(16) float ws[32][132];  // [k][col]

    const float* Wsel[4] = {W0, W1, W2, W3};
    float*       Osel[4] = {O0, O1, O2, O3};
    const float* W = Wsel[blockIdx.y];
    float*       O = Osel[blockIdx.y];
    int row0 = blockIdx.x * 128;
    int tid = threadIdx.x;
    int tr = tid >> 4, tc = tid & 15;

    float acc[8][8] = {};
    for (int kk = 0; kk < 128; kk += 32) {
        #pragma unroll
        for (int it = 0; it < 4; ++it) {
            int id = tid + it * 256;
            int r = id >> 3;
            int f = id & 7;
            int grow = row0 + r;
            float4 v = (grow < n)
                ? *reinterpret_cast<const float4*>(&x[(size_t)grow * 128 + kk + f * 4])
                : make_float4(0.f, 0.f, 0.f, 0.f);
            xs[f * 4 + 0][r] = v.x; xs[f * 4 + 1][r] = v.y;
            xs[f * 4 + 2][r] = v.z; xs[f * 4 + 3][r] = v.w;
        }
        #pragma unroll
        for (int it = 0; it < 4; ++it) {
            int id = tid + it * 256;
            int k = id >> 5;
            int c4 = id & 31;
            *reinterpret_cast<float4*>(&ws[k][c4 * 4]) =
                *reinterpret_cast<const float4*>(&W[(size_t)(kk + k) * 128 + c4 * 4]);
        }
        __syncthreads();
        #pragma unroll 4
        for (int k = 0; k < 32; ++k) {
            float4 a0 = *reinterpret_cast<const float4*>(&xs[k][tr * 8]);
            float4 a1 = *reinterpret_cast<const float4*>(&xs[k][tr * 8 + 4]);
            float4 b0 = *reinterpret_cast<const float4*>(&ws[k][tc * 8]);
            float4 b1 = *reinterpret_cast<const float4*>(&ws[k][tc * 8 + 4]);
            float av[8] = {a0.x, a0.y, a0.z, a0.w, a1.x, a1.y, a1.z, a1.w};
            float bv[8] = {b0.x, b0.y, b0.z, b0.w, b1.x, b1.y, b1.z, b1.w};
            #pragma unroll
            for (int i2 = 0; i2 < 8; ++i2)
                #pragma unroll
                for (int j2 = 0; j2 < 8; ++j2)
                    acc[i2][j2] += av[i2] * bv[j2];
        }
        __syncthreads();
    }
    #pragma unroll
    for (int i2 = 0; i2 < 8; ++i2) {
        int grow = row0 + tr * 8 + i2;
        if (grow < n) {
            float4 o0 = {acc[i2][0], acc[i2][1], acc[i2][2], acc[i2][3]};
            float4 o1 = {acc[i2][4], acc[i2][5], acc[i2][6], acc[i2][7]};
            *reinterpret_cast<float4*>(&O[(size_t)grow * 128 + tc * 8])     = o0;
            *reinterpret_cast<float4*>(&O[(size_t)grow * 128 + tc * 8 + 4]) = o1;
        }
    }
}

// ---- kernel 4: per-node attention, 1 WAVE = 1 node, DPP reductions ----
__global__ __launch_bounds__(256, 4) void node_attn(
    const int* __restrict__ nlist,
    const float* __restrict__ x,
    const float* __restrict__ xQK,
    const float* __restrict__ u,
    const float* __restrict__ xV,
    const float* __restrict__ xVV,
    float* __restrict__ outp, int n)
{
    __shared__ __align__(16) float Bs[4][16][132];  // per-wave x[nl] rows
    __shared__ __align__(16) int   NLs[4][16];
    __shared__ __align__(16) float Ts[4][16];

    int tid = threadIdx.x;
    int wid = tid >> 6;
    int l   = tid & 63;
    int g   = l >> 2;   // row/group 0..15
    int jj  = l & 3;    // 32-float chunk within row
    int i = blockIdx.x * 4 + wid;
    if (i >= n) return;

    int nlv = 0;
    if (l < 16) {
        nlv = nlist[(size_t)i * 16 + l];
        NLs[wid][l] = nlv;
    }
    unsigned long long mb = __ballot(l < 16 ? (nlv != n - 1) : 0);
    int nl_g = __shfl(nlv, g, 64);

    // A = xQK[nl_g] chunk jj (rotated order), B = x[nl] -> LDS (same rotation)
    float4 A[8];
    size_t rowbase = (size_t)nl_g * 128 + jj * 32;
    #pragma unroll
    for (int k4 = 0; k4 < 8; ++k4) {
        int rc = ((k4 + jj * 2) & 7) * 4;
        A[k4] = *reinterpret_cast<const float4*>(&xQK[rowbase + rc]);
    }
    #pragma unroll
    for (int k4 = 0; k4 < 8; ++k4) {
        int rc = ((k4 + jj * 2) & 7) * 4;
        float4 v = *reinterpret_cast<const float4*>(&x[rowbase + rc]);
        *reinterpret_cast<float4*>(&Bs[wid][g][jj * 32 + rc]) = v;
    }

    // s200 = xQK[i] . x[i] while the gather is in flight
    float2 qa = *reinterpret_cast<const float2*>(&xQK[(size_t)i * 128 + l * 2]);
    float2 xa = *reinterpret_cast<const float2*>(&x[(size_t)i * 128 + l * 2]);
    float s200 = qa.x * xa.x + qa.y * xa.y;
    s200 = dpp_add<DPP_XOR1>(s200);
    s200 = dpp_add<DPP_XOR2>(s200);
    s200 = dpp_add<DPP_XOR7>(s200);
    s200 = dpp_add<DPP_XOR15>(s200);
    s200 += __shfl_xor(s200, 16, 64);
    s200 += __shfl_xor(s200, 32, 64);

    wave_lds_fence();

    // stage-1: sc[c] = xQK[nl_g] . x[nl_c] (partial over chunk jj, quad DPP reduce)
    float a[16];
    {
        float sc[16];
        #pragma unroll
        for (int c = 0; c < 16; ++c) {
            float acc = 0.f;
            #pragma unroll
            for (int k4 = 0; k4 < 8; ++k4) {
                int rc = ((k4 + jj * 2) & 7) * 4;
                float4 b = *reinterpret_cast<const float4*>(&Bs[wid][c][jj * 32 + rc]);
                acc += A[k4].x * b.x + A[k4].y * b.y + A[k4].z * b.z + A[k4].w * b.w;
            }
            acc = dpp_add<DPP_XOR1>(acc);
            acc = dpp_add<DPP_XOR2>(acc);
            sc[c] = acc;
        }
        bool rlive = (mb >> g) & 1ULL;
        float m = -3.0e38f;
        #pragma unroll
        for (int c = 0; c < 16; ++c) {
            float s = sc[c];
            float slr = s > 0.f ? s : 0.01f * s;
            bool live = rlive && ((mb >> c) & 1ULL);
            float sm = (live ? slr : NEG_CONST) * SCARE;
            sc[c] = sm;
            m = fmaxf(m, sm);
        }
        float ssum = 0.f;
        #pragma unroll
        for (int c = 0; c < 16; ++c) { float p = __expf(sc[c] - m); a[c] = p; ssum += p; }
        float rs = 1.f / ssum;
        #pragma unroll
        for (int c = 0; c < 16; ++c) a[c] *= rs;
    }

    // prefetch xVV rows (addresses from LDS-read nl, no shfl); used at the end
    int nlarr[16];
    {
        int4 nlq[4];
        #pragma unroll
        for (int q4 = 0; q4 < 4; ++q4)
            nlq[q4] = *reinterpret_cast<const int4*>(&NLs[wid][q4 * 4]);
        #pragma unroll
        for (int q4 = 0; q4 < 4; ++q4) {
            nlarr[q4 * 4 + 0] = nlq[q4].x; nlarr[q4 * 4 + 1] = nlq[q4].y;
            nlarr[q4 * 4 + 2] = nlq[q4].z; nlarr[q4 * 4 + 3] = nlq[q4].w;
        }
    }
    float2 vvreg[16];
    #pragma unroll
    for (int k = 0; k < 16; ++k)
        vvreg[k] = *reinterpret_cast<const float2*>(&xVV[(size_t)nlarr[k] * 128 + l * 2]);

    // t_g = u[i] . x[nl_g]
    {
        float acc = 0.f;
        #pragma unroll
        for (int k4 = 0; k4 < 8; ++k4) {
            int rc = ((k4 + jj * 2) & 7) * 4;
            float4 uu = *reinterpret_cast<const float4*>(&u[(size_t)i * 128 + jj * 32 + rc]);
            float4 b  = *reinterpret_cast<const float4*>(&Bs[wid][g][jj * 32 + rc]);
            acc += uu.x * b.x + uu.y * b.y + uu.z * b.z + uu.w * b.w;
        }
        acc = dpp_add<DPP_XOR1>(acc);
        acc = dpp_add<DPP_XOR2>(acc);
        if (jj == 0) Ts[wid][g] = acc;
    }
    wave_lds_fence();
    float tarr[16];
    {
        #pragma unroll
        for (int q4 = 0; q4 < 4; ++q4) {
            float4 t4 = *reinterpret_cast<const float4*>(&Ts[wid][q4 * 4]);
            tarr[q4 * 4 + 0] = t4.x; tarr[q4 * 4 + 1] = t4.y;
            tarr[q4 * 4 + 2] = t4.z; tarr[q4 * 4 + 3] = t4.w;
        }
    }

    // stage-2 logit for this group (j = g+1): scare -> leaky -> mask
    float lg = 0.f;
    #pragma unroll
    for (int k = 0; k < 16; ++k) lg += a[k] * tarr[k];
    {
        float v = lg * SCARE;
        v = v > 0.f ? v : 0.01f * v;
        lg = ((mb >> g) & 1ULL) ? v : NEG_CONST;
    }
    float v0 = s200 * SCARE;
    v0 = v0 > 0.f ? v0 : 0.01f * v0;

    // max/sum over the 16 groups (values quad-replicated): xor7,xor15 via DPP + 16,32
    float m17 = lg;
    m17 = dpp_max<DPP_XOR7>(m17);
    m17 = dpp_max<DPP_XOR15>(m17);
    m17 = fmaxf(m17, __shfl_xor(m17, 16, 64));
    m17 = fmaxf(m17, __shfl_xor(m17, 32, 64));
    m17 = fmaxf(m17, v0);
    float pg = __expf(lg - m17);
    float sg = pg;
    sg = dpp_add<DPP_XOR7>(sg);
    sg = dpp_add<DPP_XOR15>(sg);
    sg += __shfl_xor(sg, 16, 64);
    sg += __shfl_xor(sg, 32, 64);
    float p0 = __expf(v0 - m17);
    float inv = 1.f / (sg + p0);
    float a2g = pg * inv;   // a2[g+1] (replicated within quad)
    float a20 = p0 * inv;

    // w[k] = sum_g a2[g+1] * a[g][k]  (2 DPP + 2 shfl per k)
    float w[16];
    #pragma unroll
    for (int k = 0; k < 16; ++k) {
        float wv = a2g * a[k];
        wv = dpp_add<DPP_XOR7>(wv);
        wv = dpp_add<DPP_XOR15>(wv);
        wv += __shfl_xor(wv, 16, 64);
        wv += __shfl_xor(wv, 32, 64);
        w[k] = wv;
    }

    // out pair (h = 2l, 2l+1): a2_0 * xV[i] + sum_k w[k] * xVV[nl_k] (prefetched)
    float2 xv = *reinterpret_cast<const float2*>(&xV[(size_t)i * 128 + l * 2]);
    float o0 = a20 * xv.x, o1 = a20 * xv.y;
    #pragma unroll
    for (int k = 0; k < 16; ++k) {
        o0 += w[k] * vvreg[k].x;
        o1 += w[k] * vvreg[k].y;
    }
    float sq = o0 * o0 + o1 * o1;
    sq = dpp_add<DPP_XOR1>(sq);
    sq = dpp_add<DPP_XOR2>(sq);
    sq = dpp_add<DPP_XOR7>(sq);
    sq = dpp_add<DPP_XOR15>(sq);
    sq += __shfl_xor(sq, 16, 64);
    sq += __shfl_xor(sq, 32, 64);
    float d = fmaxf(sqrtf(sq), 1e-12f);
    float rd = 1.f / d;
    float2 o = {o0 * rd, o1 * rd};
    *reinterpret_cast<float2*>(&outp[(size_t)i * 128 + l * 2]) = o;
}

extern "C" void kernel_launch(void* const* d_in, const int* in_sizes, int n_in,
                              void* d_out, int out_size, void* d_ws, size_t ws_size,
                              hipStream_t stream) {
    const float* x     = (const float*)d_in[0];
    const int*   nlist = (const int*)d_in[1];
    const float* Q     = (const float*)d_in[2];
    const float* K     = (const float*)d_in[3];
    const float* V     = (const float*)d_in[4];
    float* out = (float*)d_out;
    int n = in_sizes[0] / 128;   // 50000

    float* ws   = (float*)d_ws;
    float* QKt  = ws;                  // 16384
    float* MT   = ws + 16384;          // 16384
    float* VV   = ws + 32768;          // 16384
    float* xQK  = ws + 49152;
    size_t stride = (size_t)n * 128;
    float* uarr = xQK + stride;
    float* xV   = uarr + stride;
    float* xVV  = xV + stride;

    small_mm_a<<<dim3(16, 2), 256, 0, stream>>>(Q, K, V, QKt, VV);
    small_mm_b<<<dim3(16), 256, 0, stream>>>(QKt, V, MT);
    dim3 g2((n + 127) / 128, 4);
    proj_gemm<<<g2, 256, 0, stream>>>(x, QKt, MT, V, VV, xQK, uarr, xV, xVV, n);
    node_attn<<<(n + 3) / 4, 256, 0, stream>>>(nlist, x, xQK, uarr, xV, xVV, out, n);
}